// Round 5
// baseline (1985.736 us; speedup 1.0000x reference)
//
#include <hip/hip_runtime.h>
#include <hip/hip_bf16.h>

#define N_NODES 50000
#define NE      800000
#define NETOT   (NE + N_NODES)
#define NEG     0.2f

typedef unsigned short u16;
typedef unsigned int   u32;

__device__ __forceinline__ float b2f(u16 v) {
    union { float f; u32 u; } c; c.u = ((u32)v) << 16; return c.f;
}
__device__ __forceinline__ u16 f2b(float f) {
    union { float f; u32 u; } c; c.f = f;
    u32 r = c.u + 0x7FFF + ((c.u >> 16) & 1);
    return (u16)(r >> 16);
}
__device__ __forceinline__ float ldf(const void* p, int i, int fmt) {
    return fmt ? b2f(((const u16*)p)[i]) : ((const float*)p)[i];
}
// monotone float<->u32 keys for atomicMax on floats
__device__ __forceinline__ u32 fflip(float f) {
    u32 b = __float_as_uint(f);
    return (b >> 31) ? ~b : (b | 0x80000000u);
}
__device__ __forceinline__ float funflip(u32 k) {
    u32 b = (k >> 31) ? (k ^ 0x80000000u) : ~k;
    return __uint_as_float(b);
}

// ---- sentinel: fp32 0.25 in first 50000 slots (safe under either out dtype) ----
__global__ void fill_out(float* __restrict__ out) {
    int i = blockIdx.x * 256 + threadIdx.x;
    if (i < N_NODES) out[i] = 0.25f;
}

__global__ void zero_words(u32* __restrict__ p, int n) {
    int i = blockIdx.x * 256 + threadIdx.x;
    if (i < n) p[i] = 0u;
}

// probe float storage format of a tensor: dst=1 if bf16, 0 if fp32.
// samples 64 dwords; tests low-u16's bf16 exponent plausibility.
__global__ void probe_fmt(const u32* __restrict__ w, int stride, int* __restrict__ dst) {
    int l = threadIdx.x;
    u32 v = w[l * stride + 1];
    u32 e = (v >> 7) & 0xFF;
    int ok = (e >= 100 && e <= 140) ? 1 : 0;
    unsigned long long m = __ballot(ok);
    if (l == 0) dst[0] = (__popcll(m) >= 48) ? 1 : 0;
}

__global__ void zero_flag1(int* __restrict__ flag) { if (threadIdx.x == 0) flag[1] = 0; }

// edge_index int64 vs int32 probe: flag[2]=1 if int64
__global__ void detect_i64(const int* __restrict__ ei, int* __restrict__ flag) {
    int l = threadIdx.x;
    int idx = (l * 25000) | 1;
    int v = ei[idx];
    unsigned long long nz = __ballot(v != 0);
    if (l == 0) flag[2] = (nz == 0ULL) ? 1 : 0;
}

__device__ __forceinline__ void edge_sd(const int* __restrict__ ei, int f, int e,
                                        int& s, int& d) {
    if (e < NE) {
        if (f) { s = ei[2 * e]; d = ei[2 * (NE + e)]; }
        else   { s = ei[e];     d = ei[NE + e]; }
    } else {
        s = d = e - NE;   // self loop
    }
}

// ---------------- transform GEMM: XL = in@Wl+bl, XR = in@Wr+br (bf16 out) ------
__global__ __launch_bounds__(256) void gemm_xf(const void* __restrict__ inp,
        const int* __restrict__ fin, const int* __restrict__ fw,
        const void* __restrict__ Wl, const void* __restrict__ bl,
        const void* __restrict__ Wr, const void* __restrict__ br,
        u16* __restrict__ XL, u16* __restrict__ XR) {
    __shared__ float As[32 * 65];
    __shared__ float Bs[32 * 64];
    int fi = fin[0], fb = fw[0];
    int by = blockIdx.y;
    const void* W  = (by < 2) ? Wl : Wr;
    const void* bi = (by < 2) ? bl : br;
    u16* dst       = (by < 2) ? XL : XR;
    int jb = (by & 1) * 64;
    int n0 = blockIdx.x * 64;
    int tid = threadIdx.x;
    int tx = tid & 15, ty = tid >> 4;
    float acc[4][4] = {};
    for (int kb = 0; kb < 128; kb += 32) {
        for (int t = tid; t < 64 * 32; t += 256) {
            int node = t >> 5, kk = t & 31;
            int n = n0 + node;
            float v = 0.f;
            if (n < N_NODES) v = ldf(inp, n * 128 + kb + kk, fi);
            As[kk * 65 + node] = v;
        }
        for (int t = tid; t < 64 * 32; t += 256) {
            int j = t & 63, kk = t >> 6;
            Bs[kk * 64 + j] = ldf(W, (kb + kk) * 128 + jb + j, fb);
        }
        __syncthreads();
        #pragma unroll
        for (int kk = 0; kk < 32; ++kk) {
            float a0 = As[kk * 65 + ty * 4 + 0];
            float a1 = As[kk * 65 + ty * 4 + 1];
            float a2 = As[kk * 65 + ty * 4 + 2];
            float a3 = As[kk * 65 + ty * 4 + 3];
            const float4 b = *(const float4*)&Bs[kk * 64 + tx * 4];
            acc[0][0] += a0 * b.x; acc[0][1] += a0 * b.y; acc[0][2] += a0 * b.z; acc[0][3] += a0 * b.w;
            acc[1][0] += a1 * b.x; acc[1][1] += a1 * b.y; acc[1][2] += a1 * b.z; acc[1][3] += a1 * b.w;
            acc[2][0] += a2 * b.x; acc[2][1] += a2 * b.y; acc[2][2] += a2 * b.z; acc[2][3] += a2 * b.w;
            acc[3][0] += a3 * b.x; acc[3][1] += a3 * b.y; acc[3][2] += a3 * b.z; acc[3][3] += a3 * b.w;
        }
        __syncthreads();
    }
    float bj0 = ldf(bi, jb + tx * 4 + 0, fb);
    float bj1 = ldf(bi, jb + tx * 4 + 1, fb);
    float bj2 = ldf(bi, jb + tx * 4 + 2, fb);
    float bj3 = ldf(bi, jb + tx * 4 + 3, fb);
    #pragma unroll
    for (int i = 0; i < 4; i++) {
        int n = n0 + ty * 4 + i;
        if (n < N_NODES) {
            ushort4 o;
            o.x = f2b(acc[i][0] + bj0); o.y = f2b(acc[i][1] + bj1);
            o.z = f2b(acc[i][2] + bj2); o.w = f2b(acc[i][3] + bj3);
            *(ushort4*)&dst[n * 128 + jb + tx * 4] = o;
        }
    }
}

// ---------------- edge-parallel segment softmax (per head) ----------------
__global__ __launch_bounds__(256) void passA(const u16* __restrict__ XL,
        const u16* __restrict__ XR, const void* __restrict__ att,
        const int* __restrict__ flag, const int* __restrict__ ei,
        float* __restrict__ ehh, u32* __restrict__ emax_u, int h) {
    int wave = threadIdx.x >> 6, lane = threadIdx.x & 63;
    int e = blockIdx.x * 4 + wave;
    if (e >= NETOT) return;
    int s, d; edge_sd(ei, flag[2], e, s, d);
    float xl = b2f(XL[s * 128 + h * 64 + lane]);
    float xr = b2f(XR[d * 128 + h * 64 + lane]);
    float a  = ldf(att, h * 64 + lane, flag[3]);   // params-family format
    float t = xl + xr; t = (t > 0.f) ? t : NEG * t;
    float p = t * a;
    #pragma unroll
    for (int off = 1; off < 64; off <<= 1) p += __shfl_xor(p, off);
    if (lane == 0) {
        ehh[e] = p;
        atomicMax(&emax_u[h * N_NODES + d], fflip(p));
    }
}

__global__ __launch_bounds__(256) void passB(const int* __restrict__ flag,
        const int* __restrict__ ei, float* __restrict__ ehh,
        const u32* __restrict__ emax_u, float* __restrict__ denom, int h) {
    int e = blockIdx.x * 256 + threadIdx.x;
    if (e >= NETOT) return;
    int s, d; edge_sd(ei, flag[2], e, s, d);
    float m = funflip(emax_u[h * N_NODES + d]);
    float ex = __expf(ehh[e] - m);
    ehh[e] = ex;
    atomicAdd(&denom[h * N_NODES + d], ex);
}

__global__ __launch_bounds__(256) void passC(const u16* __restrict__ XL,
        const int* __restrict__ flag, const int* __restrict__ ei,
        const float* __restrict__ ehh, const float* __restrict__ denom,
        float* __restrict__ OUT, int h) {
    int wave = threadIdx.x >> 6, lane = threadIdx.x & 63;
    int e = blockIdx.x * 4 + wave;
    if (e >= NETOT) return;
    int s, d; edge_sd(ei, flag[2], e, s, d);
    float alpha = ehh[e] / (denom[h * N_NODES + d] + 1e-16f);
    float xl = b2f(XL[s * 128 + h * 64 + lane]);
    atomicAdd(&OUT[d * 128 + h * 64 + lane], alpha * xl);
}

// ---------------- GraphNorm ----------------
__global__ void zero_small(float* __restrict__ p) { p[threadIdx.x] = 0.f; }

__global__ __launch_bounds__(256) void colstats(const float* __restrict__ OUT,
        const void* __restrict__ bias, const int* __restrict__ fmt,
        float* __restrict__ S1, float* __restrict__ S2) {
    __shared__ float sh1[256], sh2[256];
    int tid = threadIdx.x;
    int c = tid & 127, half = tid >> 7;
    float bf = ldf(bias, c, fmt[0]);
    float s1 = 0.f, s2 = 0.f;
    for (int r = blockIdx.x * 2 + half; r < N_NODES; r += gridDim.x * 2) {
        float t = OUT[r * 128 + c] + bf;
        s1 += t; s2 += t * t;
    }
    sh1[tid] = s1; sh2[tid] = s2; __syncthreads();
    if (tid < 128) {
        atomicAdd(&S1[c], sh1[tid] + sh1[tid + 128]);
        atomicAdd(&S2[c], sh2[tid] + sh2[tid + 128]);
    }
}

__global__ void finalize_norm(const float* __restrict__ S1, const float* __restrict__ S2,
        const void* __restrict__ gamma, const void* __restrict__ beta,
        const void* __restrict__ msc, const void* __restrict__ bias,
        const int* __restrict__ fmt,
        float* __restrict__ scaleA, float* __restrict__ shiftB) {
    int c = threadIdx.x;
    if (c >= 128) return;
    int fb = fmt[0];
    const float invN = 1.f / (float)N_NODES;
    float mean = S1[c] * invN;
    float ex2  = S2[c] * invN;
    float ms = ldf(msc, c, fb);
    float var = ex2 - 2.f * ms * mean * mean + ms * ms * mean * mean;
    float rstd = rsqrtf(var + 1e-5f);
    float A = ldf(gamma, c, fb) * rstd;
    scaleA[c] = A;
    shiftB[c] = ldf(beta, c, fb) - A * (ms * mean - ldf(bias, c, fb));
}

__global__ __launch_bounds__(256) void norm_relu(float4* __restrict__ OUT,
        const float4* __restrict__ scaleA, const float4* __restrict__ shiftB) {
    int i = blockIdx.x * 256 + threadIdx.x;
    if (i >= N_NODES * 32) return;
    float4 o = OUT[i];
    int cg = i & 31;
    float4 A = scaleA[cg], B = shiftB[cg];
    float4 r;
    r.x = fmaxf(o.x * A.x + B.x, 0.f);
    r.y = fmaxf(o.y * A.y + B.y, 0.f);
    r.z = fmaxf(o.z * A.z + B.z, 0.f);
    r.w = fmaxf(o.w * A.w + B.w, 0.f);
    OUT[i] = r;
}

// ---------------- fused MLP head: OUTPUT IS FP32 ----------------
__global__ __launch_bounds__(256) void mlp_kernel(const float* __restrict__ H,
        const void* __restrict__ w1, const void* __restrict__ b1,
        const void* __restrict__ w2, const void* __restrict__ b2,
        const int* __restrict__ fmt,
        float* __restrict__ out) {
    __shared__ float W1s[128 * 64];
    __shared__ float W2s[128];
    __shared__ float b1s[64];
    int tid = threadIdx.x;
    int fb = fmt[0];
    for (int t = tid; t < 128 * 64; t += 256) W1s[t] = ldf(w1, t, fb);
    if (tid < 128) W2s[tid] = ldf(w2, tid, fb);
    if (tid < 64)  b1s[tid] = ldf(b1, tid, fb);
    __syncthreads();
    int n = blockIdx.x * 256 + tid;
    if (n >= N_NODES) return;
    float z[64];
    #pragma unroll
    for (int j = 0; j < 64; j++) z[j] = b1s[j];
    for (int kb = 0; kb < 128; kb += 16) {
        float h[16];
        #pragma unroll
        for (int t = 0; t < 4; t++) {
            float4 v = *(const float4*)&H[n * 128 + kb + t * 4];
            h[4 * t] = v.x; h[4 * t + 1] = v.y; h[4 * t + 2] = v.z; h[4 * t + 3] = v.w;
        }
        #pragma unroll
        for (int i = 0; i < 16; i++) {
            float hv = h[i];
            const float* wrow = &W1s[(kb + i) * 64];
            #pragma unroll
            for (int j = 0; j < 64; j += 4) {
                const float4 w = *(const float4*)&wrow[j];
                z[j]     += hv * w.x;
                z[j + 1] += hv * w.y;
                z[j + 2] += hv * w.z;
                z[j + 3] += hv * w.w;
            }
        }
    }
    float o0 = ldf(b2, 0, fb), o1 = ldf(b2, 1, fb);
    #pragma unroll
    for (int j = 0; j < 64; j++) {
        float zr = fmaxf(z[j], 0.f);
        o0 += zr * W2s[j * 2];
        o1 += zr * W2s[j * 2 + 1];
    }
    if (o0 != o0) o0 = 12345.f;   // NaN canary
    if (o1 != o1) o1 = 12345.f;
    float2 o; o.x = o0; o.y = o1;
    ((float2*)out)[n] = o;        // fp32 output, (N,2) row-major
}

// ---------------- launch ----------------
extern "C" void kernel_launch(void* const* d_in, const int* in_sizes, int n_in,
                              void* d_out, int out_size, void* d_ws, size_t ws_size,
                              hipStream_t stream) {
    (void)in_sizes; (void)n_in; (void)out_size; (void)ws_size;
    const void* x    = d_in[0];
    const int*  ei   = (const int*)d_in[1];
    const void* Wl0  = d_in[2];
    const void* bl0  = d_in[3];
    const void* Wr0  = d_in[4];
    const void* br0  = d_in[5];
    const void* att0 = d_in[6];
    const void* bias0= d_in[7];
    const void* Wl1  = d_in[8];
    const void* bl1  = d_in[9];
    const void* Wr1  = d_in[10];
    const void* br1  = d_in[11];
    const void* att1 = d_in[12];
    const void* bias1= d_in[13];
    const void* g0   = d_in[14];
    const void* be0  = d_in[15];
    const void* ms0  = d_in[16];
    const void* g1   = d_in[17];
    const void* be1  = d_in[18];
    const void* ms1  = d_in[19];
    const void* W1   = d_in[20];
    const void* b1   = d_in[21];
    const void* W2   = d_in[22];
    const void* b2   = d_in[23];

    char* ws = (char*)d_ws;
    const size_t NF2 = (size_t)N_NODES * 128 * 2;   // 12.8 MB bf16
    const size_t NF4 = (size_t)N_NODES * 128 * 4;   // 25.6 MB fp32
    u16*   XLb = (u16*)(ws);
    u16*   XRb = (u16*)(ws + NF2);
    float* B2  = (float*)(ws + 2 * NF2);
    char* small = ws + 2 * NF2 + NF4;               // 51.2 MB offset
    float* S1     = (float*)(small);
    float* S2     = (float*)(small + 512);
    float* scaleA = (float*)(small + 1024);
    float* shiftB = (float*)(small + 1536);
    int*   flag   = (int*)(small + 2048);  // [0]=x bf16 [1]=0 [2]=i64 [3]=params bf16
    u32*   emax_u = (u32*)(small + 4096);
    float* denom  = (float*)(small + 4096 + 400000);
    float* ehh    = (float*)(small + 4096 + 800000);
    // footprint ~55.5 MB

    const int* fX   = &flag[0];
    const int* fFP  = &flag[1];
    const int* fPar = &flag[3];
    const int GE4 = (NETOT + 3) / 4;
    const int GE256 = (NETOT + 255) / 256;

    fill_out<<<(N_NODES + 255) / 256, 256, 0, stream>>>((float*)d_out);
    probe_fmt<<<1, 64, 0, stream>>>((const u32*)x, 50000, &flag[0]);   // x: 3.2M+ dwords
    probe_fmt<<<1, 64, 0, stream>>>((const u32*)Wl0, 128, &flag[3]);   // Wl0: >=8192 dwords
    zero_flag1<<<1, 64, 0, stream>>>(flag);
    detect_i64<<<1, 64, 0, stream>>>(ei, flag);

    dim3 ggemm((N_NODES + 63) / 64, 4);

    for (int layer = 0; layer < 2; ++layer) {
        const void* Wl = layer ? Wl1 : Wl0;  const void* bl = layer ? bl1 : bl0;
        const void* Wr = layer ? Wr1 : Wr0;  const void* br = layer ? br1 : br0;
        const void* at = layer ? att1 : att0;
        const void* bi = layer ? bias1 : bias0;
        const void* gm = layer ? g1 : g0;    const void* bt = layer ? be1 : be0;
        const void* mS = layer ? ms1 : ms0;
        const void* inp = layer ? (const void*)B2 : x;
        const int* fin  = layer ? fFP : fX;

        zero_small<<<1, 256, 0, stream>>>(S1);
        zero_words<<<(200000 + 255) / 256, 256, 0, stream>>>(emax_u, 200000);
        gemm_xf<<<ggemm, 256, 0, stream>>>(inp, fin, fPar, Wl, bl, Wr, br, XLb, XRb);
        zero_words<<<(6400000 + 255) / 256, 256, 0, stream>>>((u32*)B2, 6400000);
        for (int h = 0; h < 2; ++h) {
            passA<<<GE4, 256, 0, stream>>>(XLb, XRb, at, flag, ei, ehh, emax_u, h);
            passB<<<GE256, 256, 0, stream>>>(flag, ei, ehh, emax_u, denom, h);
            passC<<<GE4, 256, 0, stream>>>(XLb, flag, ei, ehh, denom, B2, h);
        }
        colstats<<<256, 256, 0, stream>>>(B2, bi, fPar, S1, S2);
        finalize_norm<<<1, 128, 0, stream>>>(S1, S2, gm, bt, mS, bi, fPar, scaleA, shiftB);
        norm_relu<<<(N_NODES * 32 + 255) / 256, 256, 0, stream>>>((float4*)B2,
            (const float4*)scaleA, (const float4*)shiftB);
    }

    mlp_kernel<<<(N_NODES + 255) / 256, 256, 0, stream>>>(B2, W1, b1, W2, b2, fPar,
                                                          (float*)d_out);
}

// Round 6
// 752.778 us; speedup vs baseline: 2.6379x; 2.6379x over previous
//
#include <hip/hip_runtime.h>
#include <hip/hip_bf16.h>

#define N_NODES 50000
#define NE      800000
#define NETOT   (NE + N_NODES)
#define NEG     0.2f

typedef unsigned short u16;
typedef unsigned int   u32;

__device__ __forceinline__ float b2f(u16 v) {
    union { float f; u32 u; } c; c.u = ((u32)v) << 16; return c.f;
}
__device__ __forceinline__ u16 f2b(float f) {
    union { float f; u32 u; } c; c.f = f;
    u32 r = c.u + 0x7FFF + ((c.u >> 16) & 1);
    return (u16)(r >> 16);
}
__device__ __forceinline__ float ldf(const void* p, int i, int fmt) {
    return fmt ? b2f(((const u16*)p)[i]) : ((const float*)p)[i];
}

// ---- sentinel ----
__global__ void fill_out(float* __restrict__ out) {
    int i = blockIdx.x * 256 + threadIdx.x;
    if (i < N_NODES) out[i] = 0.25f;
}

// probe float storage format: dst=1 if bf16, 0 if fp32
__global__ void probe_fmt(const u32* __restrict__ w, int stride, int* __restrict__ dst) {
    int l = threadIdx.x;
    u32 v = w[l * stride + 1];
    u32 e = (v >> 7) & 0xFF;
    int ok = (e >= 100 && e <= 140) ? 1 : 0;
    unsigned long long m = __ballot(ok);
    if (l == 0) dst[0] = (__popcll(m) >= 48) ? 1 : 0;
}

__global__ void zero_flag1(int* __restrict__ flag) { if (threadIdx.x == 0) flag[1] = 0; }

// edge_index int64 vs int32 probe: flag[2]=1 if int64
__global__ void detect_i64(const int* __restrict__ ei, int* __restrict__ flag) {
    int l = threadIdx.x;
    int idx = (l * 25000) | 1;
    int v = ei[idx];
    unsigned long long nz = __ballot(v != 0);
    if (l == 0) flag[2] = (nz == 0ULL) ? 1 : 0;
}

// ---------------- CSR build (counting sort by dst, self-loops included) -------
__global__ void init_cnt(int* __restrict__ cnt) {
    int n = blockIdx.x * 256 + threadIdx.x;
    if (n < N_NODES) cnt[n] = 1;       // self loop
}

__global__ void hist_kernel(const int* __restrict__ ei, const int* __restrict__ flag,
                            int* __restrict__ cnt) {
    int e = blockIdx.x * 256 + threadIdx.x;
    if (e >= NE) return;
    int f = flag[2];
    int d = f ? ei[2 * (NE + e)] : ei[NE + e];
    atomicAdd(&cnt[d], 1);
}

#define SCAN_CHUNK 2048
__global__ void scan_a(const int* __restrict__ cnt, int* __restrict__ bsum) {
    __shared__ int sh[256];
    int b = blockIdx.x, tid = threadIdx.x;
    int base = b * SCAN_CHUNK + tid * 8;
    int s = 0;
    for (int t = 0; t < 8; t++) { int i = base + t; if (i < N_NODES) s += cnt[i]; }
    sh[tid] = s; __syncthreads();
    for (int off = 128; off > 0; off >>= 1) {
        if (tid < off) sh[tid] += sh[tid + off];
        __syncthreads();
    }
    if (tid == 0) bsum[b] = sh[0];
}

__global__ void scan_b(const int* __restrict__ bsum, int* __restrict__ boff, int nb) {
    if (threadIdx.x == 0) {
        int r = 0;
        for (int i = 0; i < nb; i++) { boff[i] = r; r += bsum[i]; }
    }
}

__global__ void scan_c(const int* __restrict__ cnt, const int* __restrict__ boff,
                       int* __restrict__ indptr, int* __restrict__ cursor) {
    __shared__ int sh[256];
    int b = blockIdx.x, tid = threadIdx.x;
    int base = b * SCAN_CHUNK + tid * 8;
    int x[8]; int s = 0;
    for (int t = 0; t < 8; t++) { int i = base + t; x[t] = (i < N_NODES) ? cnt[i] : 0; s += x[t]; }
    sh[tid] = s; __syncthreads();
    for (int off = 1; off < 256; off <<= 1) {
        int u = 0;
        if (tid >= off) u = sh[tid - off];
        __syncthreads();
        sh[tid] += u;
        __syncthreads();
    }
    int excl = sh[tid] - s;
    int run = boff[b] + excl;
    for (int t = 0; t < 8; t++) {
        int i = base + t;
        if (i < N_NODES) {
            indptr[i] = run; cursor[i] = run;
            run += x[t];
            if (i == N_NODES - 1) indptr[N_NODES] = run;
        }
    }
}

__global__ void scatter_kernel(const int* __restrict__ ei, const int* __restrict__ flag,
                               int* __restrict__ cursor, int* __restrict__ srcs) {
    int e = blockIdx.x * 256 + threadIdx.x;
    if (e >= NETOT) return;
    int f = flag[2];
    int s, d;
    if (e < NE) {
        if (f) { s = ei[2 * e]; d = ei[2 * (NE + e)]; }
        else   { s = ei[e];     d = ei[NE + e]; }
    } else {
        s = d = e - NE;
    }
    int pos = atomicAdd(&cursor[d], 1);
    srcs[pos] = s;
}

// ---------------- transform GEMM: XL = in@Wl+bl, XR = in@Wr+br (bf16 out) ------
__global__ __launch_bounds__(256) void gemm_xf(const void* __restrict__ inp,
        const int* __restrict__ fin, const int* __restrict__ fw,
        const void* __restrict__ Wl, const void* __restrict__ bl,
        const void* __restrict__ Wr, const void* __restrict__ br,
        u16* __restrict__ XL, u16* __restrict__ XR) {
    __shared__ float As[32 * 65];
    __shared__ float Bs[32 * 64];
    int fi = fin[0], fb = fw[0];
    int by = blockIdx.y;
    const void* W  = (by < 2) ? Wl : Wr;
    const void* bi = (by < 2) ? bl : br;
    u16* dst       = (by < 2) ? XL : XR;
    int jb = (by & 1) * 64;
    int n0 = blockIdx.x * 64;
    int tid = threadIdx.x;
    int tx = tid & 15, ty = tid >> 4;
    float acc[4][4] = {};
    for (int kb = 0; kb < 128; kb += 32) {
        for (int t = tid; t < 64 * 32; t += 256) {
            int node = t >> 5, kk = t & 31;
            int n = n0 + node;
            float v = 0.f;
            if (n < N_NODES) v = ldf(inp, n * 128 + kb + kk, fi);
            As[kk * 65 + node] = v;
        }
        for (int t = tid; t < 64 * 32; t += 256) {
            int j = t & 63, kk = t >> 6;
            Bs[kk * 64 + j] = ldf(W, (kb + kk) * 128 + jb + j, fb);
        }
        __syncthreads();
        #pragma unroll
        for (int kk = 0; kk < 32; ++kk) {
            float a0 = As[kk * 65 + ty * 4 + 0];
            float a1 = As[kk * 65 + ty * 4 + 1];
            float a2 = As[kk * 65 + ty * 4 + 2];
            float a3 = As[kk * 65 + ty * 4 + 3];
            const float4 b = *(const float4*)&Bs[kk * 64 + tx * 4];
            acc[0][0] += a0 * b.x; acc[0][1] += a0 * b.y; acc[0][2] += a0 * b.z; acc[0][3] += a0 * b.w;
            acc[1][0] += a1 * b.x; acc[1][1] += a1 * b.y; acc[1][2] += a1 * b.z; acc[1][3] += a1 * b.w;
            acc[2][0] += a2 * b.x; acc[2][1] += a2 * b.y; acc[2][2] += a2 * b.z; acc[2][3] += a2 * b.w;
            acc[3][0] += a3 * b.x; acc[3][1] += a3 * b.y; acc[3][2] += a3 * b.z; acc[3][3] += a3 * b.w;
        }
        __syncthreads();
    }
    float bj0 = ldf(bi, jb + tx * 4 + 0, fb);
    float bj1 = ldf(bi, jb + tx * 4 + 1, fb);
    float bj2 = ldf(bi, jb + tx * 4 + 2, fb);
    float bj3 = ldf(bi, jb + tx * 4 + 3, fb);
    #pragma unroll
    for (int i = 0; i < 4; i++) {
        int n = n0 + ty * 4 + i;
        if (n < N_NODES) {
            ushort4 o;
            o.x = f2b(acc[i][0] + bj0); o.y = f2b(acc[i][1] + bj1);
            o.z = f2b(acc[i][2] + bj2); o.w = f2b(acc[i][3] + bj3);
            *(ushort4*)&dst[n * 128 + jb + tx * 4] = o;
        }
    }
}

// ------ per-dst-node online-softmax aggregation: 1 wave/node, no atomics ------
__global__ __launch_bounds__(256) void agg_kernel(const u16* __restrict__ XL,
        const u16* __restrict__ XR, const void* __restrict__ att,
        const int* __restrict__ fmt,
        const int* __restrict__ indptr, const int* __restrict__ srcs,
        float* __restrict__ OUT) {
    int wave = threadIdx.x >> 6;
    int lane = threadIdx.x & 63;
    int n = blockIdx.x * 4 + wave;
    if (n >= N_NODES) return;
    int fb = fmt[0];
    float xr0 = b2f(XR[n * 128 + lane]);
    float xr1 = b2f(XR[n * 128 + 64 + lane]);
    float a0 = ldf(att, lane, fb);
    float a1 = ldf(att, 64 + lane, fb);
    int beg = indptr[n], end = indptr[n + 1];
    float m0 = -1e30f, d0 = 0.f, acc0 = 0.f;
    float m1 = -1e30f, d1 = 0.f, acc1 = 0.f;
    for (int i = beg; i < end; ++i) {
        int s = srcs[i];
        float xl0 = b2f(XL[s * 128 + lane]);
        float xl1 = b2f(XL[s * 128 + 64 + lane]);
        float t0 = xl0 + xr0; t0 = (t0 > 0.f) ? t0 : NEG * t0;
        float t1 = xl1 + xr1; t1 = (t1 > 0.f) ? t1 : NEG * t1;
        float p0 = t0 * a0, p1 = t1 * a1;
        #pragma unroll
        for (int off = 1; off < 64; off <<= 1) {
            p0 += __shfl_xor(p0, off);
            p1 += __shfl_xor(p1, off);
        }
        float nm0 = fmaxf(m0, p0); float sc0 = __expf(m0 - nm0); float w0 = __expf(p0 - nm0);
        acc0 = acc0 * sc0 + w0 * xl0; d0 = d0 * sc0 + w0; m0 = nm0;
        float nm1 = fmaxf(m1, p1); float sc1 = __expf(m1 - nm1); float w1 = __expf(p1 - nm1);
        acc1 = acc1 * sc1 + w1 * xl1; d1 = d1 * sc1 + w1; m1 = nm1;
    }
    OUT[n * 128 + lane]      = acc0 / (d0 + 1e-16f);
    OUT[n * 128 + 64 + lane] = acc1 / (d1 + 1e-16f);
}

// ---------------- GraphNorm ----------------
__global__ void zero_small(float* __restrict__ p) { p[threadIdx.x] = 0.f; }

__global__ __launch_bounds__(256) void colstats(const float* __restrict__ OUT,
        const void* __restrict__ bias, const int* __restrict__ fmt,
        float* __restrict__ S1, float* __restrict__ S2) {
    __shared__ float sh1[256], sh2[256];
    int tid = threadIdx.x;
    int c = tid & 127, half = tid >> 7;
    float bf = ldf(bias, c, fmt[0]);
    float s1 = 0.f, s2 = 0.f;
    for (int r = blockIdx.x * 2 + half; r < N_NODES; r += gridDim.x * 2) {
        float t = OUT[r * 128 + c] + bf;
        s1 += t; s2 += t * t;
    }
    sh1[tid] = s1; sh2[tid] = s2; __syncthreads();
    if (tid < 128) {
        atomicAdd(&S1[c], sh1[tid] + sh1[tid + 128]);
        atomicAdd(&S2[c], sh2[tid] + sh2[tid + 128]);
    }
}

__global__ void finalize_norm(const float* __restrict__ S1, const float* __restrict__ S2,
        const void* __restrict__ gamma, const void* __restrict__ beta,
        const void* __restrict__ msc, const void* __restrict__ bias,
        const int* __restrict__ fmt,
        float* __restrict__ scaleA, float* __restrict__ shiftB) {
    int c = threadIdx.x;
    if (c >= 128) return;
    int fb = fmt[0];
    const float invN = 1.f / (float)N_NODES;
    float mean = S1[c] * invN;
    float ex2  = S2[c] * invN;
    float ms = ldf(msc, c, fb);
    float var = ex2 - 2.f * ms * mean * mean + ms * ms * mean * mean;
    float rstd = rsqrtf(var + 1e-5f);
    float A = ldf(gamma, c, fb) * rstd;
    scaleA[c] = A;
    shiftB[c] = ldf(beta, c, fb) - A * (ms * mean - ldf(bias, c, fb));
}

__global__ __launch_bounds__(256) void norm_relu(float4* __restrict__ OUT,
        const float4* __restrict__ scaleA, const float4* __restrict__ shiftB) {
    int i = blockIdx.x * 256 + threadIdx.x;
    if (i >= N_NODES * 32) return;
    float4 o = OUT[i];
    int cg = i & 31;
    float4 A = scaleA[cg], B = shiftB[cg];
    float4 r;
    r.x = fmaxf(o.x * A.x + B.x, 0.f);
    r.y = fmaxf(o.y * A.y + B.y, 0.f);
    r.z = fmaxf(o.z * A.z + B.z, 0.f);
    r.w = fmaxf(o.w * A.w + B.w, 0.f);
    OUT[i] = r;
}

// ---------------- fused MLP head: fp32 output ----------------
__global__ __launch_bounds__(256) void mlp_kernel(const float* __restrict__ H,
        const void* __restrict__ w1, const void* __restrict__ b1,
        const void* __restrict__ w2, const void* __restrict__ b2,
        const int* __restrict__ fmt,
        float* __restrict__ out) {
    __shared__ float W1s[128 * 64];
    __shared__ float W2s[128];
    __shared__ float b1s[64];
    int tid = threadIdx.x;
    int fb = fmt[0];
    for (int t = tid; t < 128 * 64; t += 256) W1s[t] = ldf(w1, t, fb);
    if (tid < 128) W2s[tid] = ldf(w2, tid, fb);
    if (tid < 64)  b1s[tid] = ldf(b1, tid, fb);
    __syncthreads();
    int n = blockIdx.x * 256 + tid;
    if (n >= N_NODES) return;
    float z[64];
    #pragma unroll
    for (int j = 0; j < 64; j++) z[j] = b1s[j];
    for (int kb = 0; kb < 128; kb += 16) {
        float h[16];
        #pragma unroll
        for (int t = 0; t < 4; t++) {
            float4 v = *(const float4*)&H[n * 128 + kb + t * 4];
            h[4 * t] = v.x; h[4 * t + 1] = v.y; h[4 * t + 2] = v.z; h[4 * t + 3] = v.w;
        }
        #pragma unroll
        for (int i = 0; i < 16; i++) {
            float hv = h[i];
            const float* wrow = &W1s[(kb + i) * 64];
            #pragma unroll
            for (int j = 0; j < 64; j += 4) {
                const float4 w = *(const float4*)&wrow[j];
                z[j]     += hv * w.x;
                z[j + 1] += hv * w.y;
                z[j + 2] += hv * w.z;
                z[j + 3] += hv * w.w;
            }
        }
    }
    float o0 = ldf(b2, 0, fb), o1 = ldf(b2, 1, fb);
    #pragma unroll
    for (int j = 0; j < 64; j++) {
        float zr = fmaxf(z[j], 0.f);
        o0 += zr * W2s[j * 2];
        o1 += zr * W2s[j * 2 + 1];
    }
    if (o0 != o0) o0 = 12345.f;   // NaN canary
    if (o1 != o1) o1 = 12345.f;
    float2 o; o.x = o0; o.y = o1;
    ((float2*)out)[n] = o;
}

// ---------------- launch ----------------
extern "C" void kernel_launch(void* const* d_in, const int* in_sizes, int n_in,
                              void* d_out, int out_size, void* d_ws, size_t ws_size,
                              hipStream_t stream) {
    (void)in_sizes; (void)n_in; (void)out_size; (void)ws_size;
    const void* x    = d_in[0];
    const int*  ei   = (const int*)d_in[1];
    const void* Wl0  = d_in[2];
    const void* bl0  = d_in[3];
    const void* Wr0  = d_in[4];
    const void* br0  = d_in[5];
    const void* att0 = d_in[6];
    const void* bias0= d_in[7];
    const void* Wl1  = d_in[8];
    const void* bl1  = d_in[9];
    const void* Wr1  = d_in[10];
    const void* br1  = d_in[11];
    const void* att1 = d_in[12];
    const void* bias1= d_in[13];
    const void* g0   = d_in[14];
    const void* be0  = d_in[15];
    const void* ms0  = d_in[16];
    const void* g1   = d_in[17];
    const void* be1  = d_in[18];
    const void* ms1  = d_in[19];
    const void* W1   = d_in[20];
    const void* b1   = d_in[21];
    const void* W2   = d_in[22];
    const void* b2   = d_in[23];

    char* ws = (char*)d_ws;
    const size_t NF2 = (size_t)N_NODES * 128 * 2;   // 12.8 MB bf16
    const size_t NF4 = (size_t)N_NODES * 128 * 4;   // 25.6 MB fp32
    u16*   XLb = (u16*)(ws);
    u16*   XRb = (u16*)(ws + NF2);
    float* B2  = (float*)(ws + 2 * NF2);
    char* small = ws + 2 * NF2 + NF4;               // 51.2 MB offset
    float* S1     = (float*)(small);
    float* S2     = (float*)(small + 512);
    float* scaleA = (float*)(small + 1024);
    float* shiftB = (float*)(small + 1536);
    int*   flag   = (int*)(small + 2048);  // [0]=x bf16 [1]=0 [2]=i64 [3]=params bf16
    int*   bsum   = (int*)(small + 2112);
    int*   boff   = (int*)(small + 2368);
    int*   indptr = (int*)(small + 4096);
    int*   cursor = indptr + (N_NODES + 64);
    int*   cnt    = cursor + (N_NODES + 64);
    int*   srcs   = cnt + (N_NODES + 64);
    // footprint ~55.2 MB (within the proven-working budget)

    const int* fX   = &flag[0];
    const int* fFP  = &flag[1];
    const int* fPar = &flag[3];
    const int NB_SCAN = (N_NODES + SCAN_CHUNK - 1) / SCAN_CHUNK;  // 25

    fill_out<<<(N_NODES + 255) / 256, 256, 0, stream>>>((float*)d_out);
    probe_fmt<<<1, 64, 0, stream>>>((const u32*)x, 50000, &flag[0]);
    probe_fmt<<<1, 64, 0, stream>>>((const u32*)Wl0, 128, &flag[3]);
    zero_flag1<<<1, 64, 0, stream>>>(flag);
    detect_i64<<<1, 64, 0, stream>>>(ei, flag);

    // CSR build (shared by both layers)
    init_cnt<<<(N_NODES + 255) / 256, 256, 0, stream>>>(cnt);
    hist_kernel<<<(NE + 255) / 256, 256, 0, stream>>>(ei, flag, cnt);
    scan_a<<<NB_SCAN, 256, 0, stream>>>(cnt, bsum);
    scan_b<<<1, 64, 0, stream>>>(bsum, boff, NB_SCAN);
    scan_c<<<NB_SCAN, 256, 0, stream>>>(cnt, boff, indptr, cursor);
    scatter_kernel<<<(NETOT + 255) / 256, 256, 0, stream>>>(ei, flag, cursor, srcs);

    dim3 ggemm((N_NODES + 63) / 64, 4);

    for (int layer = 0; layer < 2; ++layer) {
        const void* Wl = layer ? Wl1 : Wl0;  const void* bl = layer ? bl1 : bl0;
        const void* Wr = layer ? Wr1 : Wr0;  const void* br = layer ? br1 : br0;
        const void* at = layer ? att1 : att0;
        const void* bi = layer ? bias1 : bias0;
        const void* gm = layer ? g1 : g0;    const void* bt = layer ? be1 : be0;
        const void* mS = layer ? ms1 : ms0;
        const void* inp = layer ? (const void*)B2 : x;
        const int* fin  = layer ? fFP : fX;

        zero_small<<<1, 256, 0, stream>>>(S1);
        gemm_xf<<<ggemm, 256, 0, stream>>>(inp, fin, fPar, Wl, bl, Wr, br, XLb, XRb);
        agg_kernel<<<(N_NODES + 3) / 4, 256, 0, stream>>>(XLb, XRb, at, fPar,
                                                          indptr, srcs, B2);
        colstats<<<256, 256, 0, stream>>>(B2, bi, fPar, S1, S2);
        finalize_norm<<<1, 128, 0, stream>>>(S1, S2, gm, bt, mS, bi, fPar, scaleA, shiftB);
        norm_relu<<<(N_NODES * 32 + 255) / 256, 256, 0, stream>>>((float4*)B2,
            (const float4*)scaleA, (const float4*)shiftB);
    }

    mlp_kernel<<<(N_NODES + 255) / 256, 256, 0, stream>>>(B2, W1, b1, W2, b2, fPar,
                                                          (float*)d_out);
}

// Round 7
// 723.464 us; speedup vs baseline: 2.7448x; 1.0405x over previous
//
#include <hip/hip_runtime.h>
#include <hip/hip_bf16.h>

#define N_NODES 50000
#define NE      800000
#define NETOT   (NE + N_NODES)
#define NEG     0.2f

typedef unsigned short u16;
typedef unsigned int   u32;
typedef __attribute__((ext_vector_type(8))) short bf16x8;
typedef __attribute__((ext_vector_type(4))) float f32x4;

__device__ __forceinline__ float b2f(u16 v) {
    union { float f; u32 u; } c; c.u = ((u32)v) << 16; return c.f;
}
__device__ __forceinline__ u16 f2b(float f) {
    union { float f; u32 u; } c; c.f = f;
    u32 r = c.u + 0x7FFF + ((c.u >> 16) & 1);
    return (u16)(r >> 16);
}
__device__ __forceinline__ float ldf(const void* p, int i, int fmt) {
    return fmt ? b2f(((const u16*)p)[i]) : ((const float*)p)[i];
}
// bf16 pair packed in u32: lo = channel 2l, hi = channel 2l+1
__device__ __forceinline__ float wlo(u32 w) { return __uint_as_float(w << 16); }
__device__ __forceinline__ float whi(u32 w) { return __uint_as_float(w & 0xffff0000u); }

// ---- sentinel ----
__global__ void fill_out(float* __restrict__ out) {
    int i = blockIdx.x * 256 + threadIdx.x;
    if (i < N_NODES) out[i] = 0.25f;
}

// probe float storage format: dst=1 if bf16, 0 if fp32
__global__ void probe_fmt(const u32* __restrict__ w, int stride, int* __restrict__ dst) {
    int l = threadIdx.x;
    u32 v = w[l * stride + 1];
    u32 e = (v >> 7) & 0xFF;
    int ok = (e >= 100 && e <= 140) ? 1 : 0;
    unsigned long long m = __ballot(ok);
    if (l == 0) dst[0] = (__popcll(m) >= 48) ? 1 : 0;
}

__global__ void zero_flag1(int* __restrict__ flag) { if (threadIdx.x == 0) flag[1] = 0; }

// edge_index int64 vs int32 probe: flag[2]=1 if int64
__global__ void detect_i64(const int* __restrict__ ei, int* __restrict__ flag) {
    int l = threadIdx.x;
    int idx = (l * 25000) | 1;
    int v = ei[idx];
    unsigned long long nz = __ballot(v != 0);
    if (l == 0) flag[2] = (nz == 0ULL) ? 1 : 0;
}

// ---------------- CSR build (counting sort by dst, self-loops included) -------
__global__ void init_cnt(int* __restrict__ cnt) {
    int n = blockIdx.x * 256 + threadIdx.x;
    if (n < N_NODES) cnt[n] = 1;
}

__global__ void hist_kernel(const int* __restrict__ ei, const int* __restrict__ flag,
                            int* __restrict__ cnt) {
    int e = blockIdx.x * 256 + threadIdx.x;
    if (e >= NE) return;
    int f = flag[2];
    int d = f ? ei[2 * (NE + e)] : ei[NE + e];
    atomicAdd(&cnt[d], 1);
}

#define SCAN_CHUNK 2048
__global__ void scan_a(const int* __restrict__ cnt, int* __restrict__ bsum) {
    __shared__ int sh[256];
    int b = blockIdx.x, tid = threadIdx.x;
    int base = b * SCAN_CHUNK + tid * 8;
    int s = 0;
    for (int t = 0; t < 8; t++) { int i = base + t; if (i < N_NODES) s += cnt[i]; }
    sh[tid] = s; __syncthreads();
    for (int off = 128; off > 0; off >>= 1) {
        if (tid < off) sh[tid] += sh[tid + off];
        __syncthreads();
    }
    if (tid == 0) bsum[b] = sh[0];
}

__global__ void scan_b(const int* __restrict__ bsum, int* __restrict__ boff, int nb) {
    if (threadIdx.x == 0) {
        int r = 0;
        for (int i = 0; i < nb; i++) { boff[i] = r; r += bsum[i]; }
    }
}

__global__ void scan_c(const int* __restrict__ cnt, const int* __restrict__ boff,
                       int* __restrict__ indptr, int* __restrict__ cursor) {
    __shared__ int sh[256];
    int b = blockIdx.x, tid = threadIdx.x;
    int base = b * SCAN_CHUNK + tid * 8;
    int x[8]; int s = 0;
    for (int t = 0; t < 8; t++) { int i = base + t; x[t] = (i < N_NODES) ? cnt[i] : 0; s += x[t]; }
    sh[tid] = s; __syncthreads();
    for (int off = 1; off < 256; off <<= 1) {
        int u = 0;
        if (tid >= off) u = sh[tid - off];
        __syncthreads();
        sh[tid] += u;
        __syncthreads();
    }
    int excl = sh[tid] - s;
    int run = boff[b] + excl;
    for (int t = 0; t < 8; t++) {
        int i = base + t;
        if (i < N_NODES) {
            indptr[i] = run; cursor[i] = run;
            run += x[t];
            if (i == N_NODES - 1) indptr[N_NODES] = run;
        }
    }
}

__global__ void scatter_kernel(const int* __restrict__ ei, const int* __restrict__ flag,
                               int* __restrict__ cursor, int* __restrict__ srcs) {
    int e = blockIdx.x * 256 + threadIdx.x;
    if (e >= NETOT) return;
    int f = flag[2];
    int s, d;
    if (e < NE) {
        if (f) { s = ei[2 * e]; d = ei[2 * (NE + e)]; }
        else   { s = ei[e];     d = ei[NE + e]; }
    } else {
        s = d = e - NE;
    }
    int pos = atomicAdd(&cursor[d], 1);
    srcs[pos] = s;
}

// ------------- MFMA transform GEMM: XL = in@Wl+bl, XR = in@Wr+br (bf16 out) ----
// grid.y in [0,4): {Wl cols 0-63, Wl 64-127, Wr 0-63, Wr 64-127}
// LDS: A [64 nodes][128 k] bf16, B^T [64 j][128 k] bf16; rows padded +8 elems.
#define LDP 136   // padded row stride (elements): 272 B = 17*16 B, b128-aligned
__global__ __launch_bounds__(256) void gemm_xf(const void* __restrict__ inp,
        const int* __restrict__ fin, const int* __restrict__ fw,
        const void* __restrict__ Wl, const void* __restrict__ bl,
        const void* __restrict__ Wr, const void* __restrict__ br,
        u16* __restrict__ XL, u16* __restrict__ XR) {
    __shared__ u16 As16[64 * LDP];
    __shared__ u16 Bs16[64 * LDP];
    int fi = fin[0], fb = fw[0];
    int by = blockIdx.y;
    const void* W  = (by < 2) ? Wl : Wr;
    const void* bi = (by < 2) ? bl : br;
    u16* dst       = (by < 2) ? XL : XR;
    int jb = (by & 1) * 64;
    int n0 = blockIdx.x * 64;
    int tid = threadIdx.x;

    // stage A: rows = nodes, cols = k (contiguous)
    for (int t = tid; t < 64 * 128; t += 256) {
        int node = t >> 7, k = t & 127;
        int n = n0 + node;
        u16 hv = 0;
        if (n < N_NODES) {
            hv = fi ? ((const u16*)inp)[n * 128 + k]
                    : f2b(((const float*)inp)[n * 128 + k]);
        }
        As16[node * LDP + k] = hv;
    }
    // stage B transposed: rows = j (0..63 rel), cols = k
    for (int t = tid; t < 128 * 64; t += 256) {
        int k = t >> 6, j = t & 63;
        u16 hv = fb ? ((const u16*)W)[k * 128 + jb + j]
                    : f2b(((const float*)W)[k * 128 + jb + j]);
        Bs16[j * LDP + k] = hv;
    }
    __syncthreads();

    int wv = tid >> 6, lane = tid & 63;
    int quad = lane >> 4, r = lane & 15;
    int m0 = wv * 16;                       // wave's node-row base
    f32x4 acc[4] = {{0.f,0.f,0.f,0.f},{0.f,0.f,0.f,0.f},
                    {0.f,0.f,0.f,0.f},{0.f,0.f,0.f,0.f}};
    #pragma unroll
    for (int ks = 0; ks < 4; ++ks) {
        int ko = ks * 32 + quad * 8;
        bf16x8 af = *(const bf16x8*)&As16[(m0 + r) * LDP + ko];   // A[m=r][k=quad*8+j]
        #pragma unroll
        for (int t = 0; t < 4; ++t) {
            bf16x8 bfr = *(const bf16x8*)&Bs16[(t * 16 + r) * LDP + ko]; // B[k][n=r]
            acc[t] = __builtin_amdgcn_mfma_f32_16x16x32_bf16(af, bfr, acc[t], 0, 0, 0);
        }
    }
    // epilogue: D row = quad*4+reg (node), col = r (j within tile)
    #pragma unroll
    for (int t = 0; t < 4; ++t) {
        int j = jb + t * 16 + r;
        float bj = ldf(bi, j, fb);
        #pragma unroll
        for (int reg = 0; reg < 4; ++reg) {
            int node = n0 + m0 + quad * 4 + reg;
            if (node < N_NODES) dst[node * 128 + j] = f2b(acc[t][reg] + bj);
        }
    }
}

// ------ per-dst online-softmax aggregation: lane owns channel pair (2l,2l+1) ---
// lanes 0-31 = head0, lanes 32-63 = head1; 5-step butterfly reduces both heads.
__global__ __launch_bounds__(256) void agg_kernel(const u32* __restrict__ XLw,
        const u32* __restrict__ XRw, const void* __restrict__ att,
        const int* __restrict__ fmt,
        const int* __restrict__ indptr, const int* __restrict__ srcs,
        float2* __restrict__ OUT2) {
    int wave = threadIdx.x >> 6;
    int lane = threadIdx.x & 63;
    int n = blockIdx.x * 4 + wave;
    if (n >= N_NODES) return;
    int fb = fmt[0];
    u32 wr = XRw[n * 64 + lane];
    float xr0 = wlo(wr), xr1 = whi(wr);
    float a0 = ldf(att, 2 * lane, fb);
    float a1 = ldf(att, 2 * lane + 1, fb);
    int beg = indptr[n], end = indptr[n + 1];
    float m = -1e30f, d = 0.f, acc0 = 0.f, acc1 = 0.f;
    for (int i = beg; i < end; ++i) {
        int s = srcs[i];
        u32 wl = XLw[s * 64 + lane];
        float xl0 = wlo(wl), xl1 = whi(wl);
        float t0 = xl0 + xr0; t0 = (t0 > 0.f) ? t0 : NEG * t0;
        float t1 = xl1 + xr1; t1 = (t1 > 0.f) ? t1 : NEG * t1;
        float p = t0 * a0 + t1 * a1;
        p += __shfl_xor(p, 1);
        p += __shfl_xor(p, 2);
        p += __shfl_xor(p, 4);
        p += __shfl_xor(p, 8);
        p += __shfl_xor(p, 16);     // stays within each 32-lane half
        float nm = fmaxf(m, p);
        float sc = __expf(m - nm);
        float w  = __expf(p - nm);
        acc0 = acc0 * sc + w * xl0;
        acc1 = acc1 * sc + w * xl1;
        d = d * sc + w; m = nm;
    }
    float inv = 1.f / (d + 1e-16f);
    float2 o; o.x = acc0 * inv; o.y = acc1 * inv;
    OUT2[n * 64 + lane] = o;
}

// ---------------- GraphNorm ----------------
__global__ void zero_small(float* __restrict__ p) { p[threadIdx.x] = 0.f; }

__global__ __launch_bounds__(256) void colstats(const float* __restrict__ OUT,
        const void* __restrict__ bias, const int* __restrict__ fmt,
        float* __restrict__ S1, float* __restrict__ S2) {
    __shared__ float sh1[256], sh2[256];
    int tid = threadIdx.x;
    int c = tid & 127, half = tid >> 7;
    float bf = ldf(bias, c, fmt[0]);
    float s1 = 0.f, s2 = 0.f;
    for (int r = blockIdx.x * 2 + half; r < N_NODES; r += gridDim.x * 2) {
        float t = OUT[r * 128 + c] + bf;
        s1 += t; s2 += t * t;
    }
    sh1[tid] = s1; sh2[tid] = s2; __syncthreads();
    if (tid < 128) {
        atomicAdd(&S1[c], sh1[tid] + sh1[tid + 128]);
        atomicAdd(&S2[c], sh2[tid] + sh2[tid + 128]);
    }
}

__global__ void finalize_norm(const float* __restrict__ S1, const float* __restrict__ S2,
        const void* __restrict__ gamma, const void* __restrict__ beta,
        const void* __restrict__ msc, const void* __restrict__ bias,
        const int* __restrict__ fmt,
        float* __restrict__ scaleA, float* __restrict__ shiftB) {
    int c = threadIdx.x;
    if (c >= 128) return;
    int fb = fmt[0];
    const float invN = 1.f / (float)N_NODES;
    float mean = S1[c] * invN;
    float ex2  = S2[c] * invN;
    float ms = ldf(msc, c, fb);
    float var = ex2 - 2.f * ms * mean * mean + ms * ms * mean * mean;
    float rstd = rsqrtf(var + 1e-5f);
    float A = ldf(gamma, c, fb) * rstd;
    scaleA[c] = A;
    shiftB[c] = ldf(beta, c, fb) - A * (ms * mean - ldf(bias, c, fb));
}

__global__ __launch_bounds__(256) void norm_relu(float4* __restrict__ OUT,
        const float4* __restrict__ scaleA, const float4* __restrict__ shiftB) {
    int i = blockIdx.x * 256 + threadIdx.x;
    if (i >= N_NODES * 32) return;
    float4 o = OUT[i];
    int cg = i & 31;
    float4 A = scaleA[cg], B = shiftB[cg];
    float4 r;
    r.x = fmaxf(o.x * A.x + B.x, 0.f);
    r.y = fmaxf(o.y * A.y + B.y, 0.f);
    r.z = fmaxf(o.z * A.z + B.z, 0.f);
    r.w = fmaxf(o.w * A.w + B.w, 0.f);
    OUT[i] = r;
}

// ---------------- fused MLP head: fp32 output ----------------
__global__ __launch_bounds__(256) void mlp_kernel(const float* __restrict__ H,
        const void* __restrict__ w1, const void* __restrict__ b1,
        const void* __restrict__ w2, const void* __restrict__ b2,
        const int* __restrict__ fmt,
        float* __restrict__ out) {
    __shared__ float W1s[128 * 64];
    __shared__ float W2s[128];
    __shared__ float b1s[64];
    int tid = threadIdx.x;
    int fb = fmt[0];
    for (int t = tid; t < 128 * 64; t += 256) W1s[t] = ldf(w1, t, fb);
    if (tid < 128) W2s[tid] = ldf(w2, tid, fb);
    if (tid < 64)  b1s[tid] = ldf(b1, tid, fb);
    __syncthreads();
    int n = blockIdx.x * 256 + tid;
    if (n >= N_NODES) return;
    float z[64];
    #pragma unroll
    for (int j = 0; j < 64; j++) z[j] = b1s[j];
    for (int kb = 0; kb < 128; kb += 16) {
        float h[16];
        #pragma unroll
        for (int t = 0; t < 4; t++) {
            float4 v = *(const float4*)&H[n * 128 + kb + t * 4];
            h[4 * t] = v.x; h[4 * t + 1] = v.y; h[4 * t + 2] = v.z; h[4 * t + 3] = v.w;
        }
        #pragma unroll
        for (int i = 0; i < 16; i++) {
            float hv = h[i];
            const float* wrow = &W1s[(kb + i) * 64];
            #pragma unroll
            for (int j = 0; j < 64; j += 4) {
                const float4 w = *(const float4*)&wrow[j];
                z[j]     += hv * w.x;
                z[j + 1] += hv * w.y;
                z[j + 2] += hv * w.z;
                z[j + 3] += hv * w.w;
            }
        }
    }
    float o0 = ldf(b2, 0, fb), o1 = ldf(b2, 1, fb);
    #pragma unroll
    for (int j = 0; j < 64; j++) {
        float zr = fmaxf(z[j], 0.f);
        o0 += zr * W2s[j * 2];
        o1 += zr * W2s[j * 2 + 1];
    }
    if (o0 != o0) o0 = 12345.f;
    if (o1 != o1) o1 = 12345.f;
    float2 o; o.x = o0; o.y = o1;
    ((float2*)out)[n] = o;
}

// ---------------- launch ----------------
extern "C" void kernel_launch(void* const* d_in, const int* in_sizes, int n_in,
                              void* d_out, int out_size, void* d_ws, size_t ws_size,
                              hipStream_t stream) {
    (void)in_sizes; (void)n_in; (void)out_size; (void)ws_size;
    const void* x    = d_in[0];
    const int*  ei   = (const int*)d_in[1];
    const void* Wl0  = d_in[2];
    const void* bl0  = d_in[3];
    const void* Wr0  = d_in[4];
    const void* br0  = d_in[5];
    const void* att0 = d_in[6];
    const void* bias0= d_in[7];
    const void* Wl1  = d_in[8];
    const void* bl1  = d_in[9];
    const void* Wr1  = d_in[10];
    const void* br1  = d_in[11];
    const void* att1 = d_in[12];
    const void* bias1= d_in[13];
    const void* g0   = d_in[14];
    const void* be0  = d_in[15];
    const void* ms0  = d_in[16];
    const void* g1   = d_in[17];
    const void* be1  = d_in[18];
    const void* ms1  = d_in[19];
    const void* W1   = d_in[20];
    const void* b1   = d_in[21];
    const void* W2   = d_in[22];
    const void* b2   = d_in[23];

    char* ws = (char*)d_ws;
    const size_t NF2 = (size_t)N_NODES * 128 * 2;   // 12.8 MB bf16
    const size_t NF4 = (size_t)N_NODES * 128 * 4;   // 25.6 MB fp32
    u16*   XLb = (u16*)(ws);
    u16*   XRb = (u16*)(ws + NF2);
    float* B2  = (float*)(ws + 2 * NF2);
    char* small = ws + 2 * NF2 + NF4;               // 51.2 MB offset
    float* S1     = (float*)(small);
    float* S2     = (float*)(small + 512);
    float* scaleA = (float*)(small + 1024);
    float* shiftB = (float*)(small + 1536);
    int*   flag   = (int*)(small + 2048);  // [0]=x bf16 [1]=0 [2]=i64 [3]=params bf16
    int*   bsum   = (int*)(small + 2112);
    int*   boff   = (int*)(small + 2368);
    int*   indptr = (int*)(small + 4096);
    int*   cursor = indptr + (N_NODES + 64);
    int*   cnt    = cursor + (N_NODES + 64);
    int*   srcs   = cnt + (N_NODES + 64);
    // footprint ~55.2 MB (proven budget)

    const int* fX   = &flag[0];
    const int* fFP  = &flag[1];
    const int* fPar = &flag[3];
    const int NB_SCAN = (N_NODES + SCAN_CHUNK - 1) / SCAN_CHUNK;  // 25

    fill_out<<<(N_NODES + 255) / 256, 256, 0, stream>>>((float*)d_out);
    probe_fmt<<<1, 64, 0, stream>>>((const u32*)x, 50000, &flag[0]);
    probe_fmt<<<1, 64, 0, stream>>>((const u32*)Wl0, 128, &flag[3]);
    zero_flag1<<<1, 64, 0, stream>>>(flag);
    detect_i64<<<1, 64, 0, stream>>>(ei, flag);

    // CSR build (shared by both layers)
    init_cnt<<<(N_NODES + 255) / 256, 256, 0, stream>>>(cnt);
    hist_kernel<<<(NE + 255) / 256, 256, 0, stream>>>(ei, flag, cnt);
    scan_a<<<NB_SCAN, 256, 0, stream>>>(cnt, bsum);
    scan_b<<<1, 64, 0, stream>>>(bsum, boff, NB_SCAN);
    scan_c<<<NB_SCAN, 256, 0, stream>>>(cnt, boff, indptr, cursor);
    scatter_kernel<<<(NETOT + 255) / 256, 256, 0, stream>>>(ei, flag, cursor, srcs);

    dim3 ggemm((N_NODES + 63) / 64, 4);

    for (int layer = 0; layer < 2; ++layer) {
        const void* Wl = layer ? Wl1 : Wl0;  const void* bl = layer ? bl1 : bl0;
        const void* Wr = layer ? Wr1 : Wr0;  const void* br = layer ? br1 : br0;
        const void* at = layer ? att1 : att0;
        const void* bi = layer ? bias1 : bias0;
        const void* gm = layer ? g1 : g0;    const void* bt = layer ? be1 : be0;
        const void* mS = layer ? ms1 : ms0;
        const void* inp = layer ? (const void*)B2 : x;
        const int* fin  = layer ? fFP : fX;

        zero_small<<<1, 256, 0, stream>>>(S1);
        gemm_xf<<<ggemm, 256, 0, stream>>>(inp, fin, fPar, Wl, bl, Wr, br, XLb, XRb);
        agg_kernel<<<(N_NODES + 3) / 4, 256, 0, stream>>>((const u32*)XLb, (const u32*)XRb,
                                                          at, fPar, indptr, srcs,
                                                          (float2*)B2);
        colstats<<<256, 256, 0, stream>>>(B2, bi, fPar, S1, S2);
        finalize_norm<<<1, 128, 0, stream>>>(S1, S2, gm, bt, mS, bi, fPar, scaleA, shiftB);
        norm_relu<<<(N_NODES * 32 + 255) / 256, 256, 0, stream>>>((float4*)B2,
            (const float4*)scaleA, (const float4*)shiftB);
    }

    mlp_kernel<<<(N_NODES + 255) / 256, 256, 0, stream>>>(B2, W1, b1, W2, b2, fPar,
                                                          (float*)d_out);
}

// Round 8
// 516.759 us; speedup vs baseline: 3.8427x; 1.4000x over previous
//
#include <hip/hip_runtime.h>
#include <hip/hip_bf16.h>

#define N_NODES 50000
#define NE      800000
#define NETOT   (NE + N_NODES)
#define NEG     0.2f

typedef unsigned short u16;
typedef unsigned int   u32;
typedef __attribute__((ext_vector_type(8))) short bf16x8;
typedef __attribute__((ext_vector_type(4))) float f32x4;

__device__ __forceinline__ float b2f(u16 v) {
    union { float f; u32 u; } c; c.u = ((u32)v) << 16; return c.f;
}
__device__ __forceinline__ u16 f2b(float f) {
    union { float f; u32 u; } c; c.f = f;
    u32 r = c.u + 0x7FFF + ((c.u >> 16) & 1);
    return (u16)(r >> 16);
}
__device__ __forceinline__ float ldf(const void* p, int i, int fmt) {
    return fmt ? b2f(((const u16*)p)[i]) : ((const float*)p)[i];
}
__device__ __forceinline__ float wlo(u32 w) { return __uint_as_float(w << 16); }
__device__ __forceinline__ float whi(u32 w) { return __uint_as_float(w & 0xffff0000u); }

// ---- sentinel ----
__global__ void fill_out(float* __restrict__ out) {
    int i = blockIdx.x * 256 + threadIdx.x;
    if (i < N_NODES) out[i] = 0.25f;
}

// probe float storage format: dst=1 if bf16, 0 if fp32
__global__ void probe_fmt(const u32* __restrict__ w, int stride, int* __restrict__ dst) {
    int l = threadIdx.x;
    u32 v = w[l * stride + 1];
    u32 e = (v >> 7) & 0xFF;
    int ok = (e >= 100 && e <= 140) ? 1 : 0;
    unsigned long long m = __ballot(ok);
    if (l == 0) dst[0] = (__popcll(m) >= 48) ? 1 : 0;
}

__global__ void zero_flag1(int* __restrict__ flag) { if (threadIdx.x == 0) flag[1] = 0; }

__global__ void detect_i64(const int* __restrict__ ei, int* __restrict__ flag) {
    int l = threadIdx.x;
    int idx = (l * 25000) | 1;
    int v = ei[idx];
    unsigned long long nz = __ballot(v != 0);
    if (l == 0) flag[2] = (nz == 0ULL) ? 1 : 0;
}

// ---------------- CSR build ----------------
__global__ void init_cnt(int* __restrict__ cnt) {
    int n = blockIdx.x * 256 + threadIdx.x;
    if (n < N_NODES) cnt[n] = 1;
}

__global__ void hist_kernel(const int* __restrict__ ei, const int* __restrict__ flag,
                            int* __restrict__ cnt) {
    int e = blockIdx.x * 256 + threadIdx.x;
    if (e >= NE) return;
    int f = flag[2];
    int d = f ? ei[2 * (NE + e)] : ei[NE + e];
    atomicAdd(&cnt[d], 1);
}

#define SCAN_CHUNK 2048
__global__ void scan_a(const int* __restrict__ cnt, int* __restrict__ bsum) {
    __shared__ int sh[256];
    int b = blockIdx.x, tid = threadIdx.x;
    int base = b * SCAN_CHUNK + tid * 8;
    int s = 0;
    for (int t = 0; t < 8; t++) { int i = base + t; if (i < N_NODES) s += cnt[i]; }
    sh[tid] = s; __syncthreads();
    for (int off = 128; off > 0; off >>= 1) {
        if (tid < off) sh[tid] += sh[tid + off];
        __syncthreads();
    }
    if (tid == 0) bsum[b] = sh[0];
}

__global__ void scan_b(const int* __restrict__ bsum, int* __restrict__ boff, int nb) {
    if (threadIdx.x == 0) {
        int r = 0;
        for (int i = 0; i < nb; i++) { boff[i] = r; r += bsum[i]; }
    }
}

__global__ void scan_c(const int* __restrict__ cnt, const int* __restrict__ boff,
                       int* __restrict__ indptr, int* __restrict__ cursor) {
    __shared__ int sh[256];
    int b = blockIdx.x, tid = threadIdx.x;
    int base = b * SCAN_CHUNK + tid * 8;
    int x[8]; int s = 0;
    for (int t = 0; t < 8; t++) { int i = base + t; x[t] = (i < N_NODES) ? cnt[i] : 0; s += x[t]; }
    sh[tid] = s; __syncthreads();
    for (int off = 1; off < 256; off <<= 1) {
        int u = 0;
        if (tid >= off) u = sh[tid - off];
        __syncthreads();
        sh[tid] += u;
        __syncthreads();
    }
    int excl = sh[tid] - s;
    int run = boff[b] + excl;
    for (int t = 0; t < 8; t++) {
        int i = base + t;
        if (i < N_NODES) {
            indptr[i] = run; cursor[i] = run;
            run += x[t];
            if (i == N_NODES - 1) indptr[N_NODES] = run;
        }
    }
}

__global__ void scatter_kernel(const int* __restrict__ ei, const int* __restrict__ flag,
                               int* __restrict__ cursor, int* __restrict__ srcs) {
    int e = blockIdx.x * 256 + threadIdx.x;
    if (e >= NETOT) return;
    int f = flag[2];
    int s, d;
    if (e < NE) {
        if (f) { s = ei[2 * e]; d = ei[2 * (NE + e)]; }
        else   { s = ei[e];     d = ei[NE + e]; }
    } else {
        s = d = e - NE;
    }
    int pos = atomicAdd(&cursor[d], 1);
    srcs[pos] = s;
}

// ------------- MFMA transform GEMM with optional fused input-norm -------------
// grid.y in [0,4): {Wl cols 0-63, Wl 64-127, Wr 0-63, Wr 64-127}
// nscale/nshift != null: input = max(raw*scale+shift, 0) (GraphNorm+ReLU fused)
#define LDP 136
__global__ __launch_bounds__(256) void gemm_xf(const void* __restrict__ inp,
        const int* __restrict__ fin, const int* __restrict__ fw,
        const void* __restrict__ Wl, const void* __restrict__ bl,
        const void* __restrict__ Wr, const void* __restrict__ br,
        const float* __restrict__ nscale, const float* __restrict__ nshift,
        u16* __restrict__ XL, u16* __restrict__ XR) {
    __shared__ u16 As16[64 * LDP];
    __shared__ u16 Bs16[64 * LDP];
    __shared__ float Sc[128], Sh[128];
    int fi = fin[0], fb = fw[0];
    int by = blockIdx.y;
    const void* W  = (by < 2) ? Wl : Wr;
    const void* bi = (by < 2) ? bl : br;
    u16* dst       = (by < 2) ? XL : XR;
    int jb = (by & 1) * 64;
    int n0 = blockIdx.x * 64;
    int tid = threadIdx.x;
    bool donorm = (nscale != nullptr);
    if (donorm) {
        if (tid < 128) { Sc[tid] = nscale[tid]; Sh[tid] = nshift[tid]; }
        __syncthreads();
    }

    // stage A [64 nodes][128 k]
    if (fi) {   // bf16 input (never normed): 16B vector loads
        for (int t = tid; t < 64 * 16; t += 256) {
            int node = t >> 4, c8 = (t & 15) << 3;
            int n = n0 + node;
            bf16x8 v = {0,0,0,0,0,0,0,0};
            if (n < N_NODES) v = *(const bf16x8*)((const u16*)inp + (size_t)n * 128 + c8);
            *(bf16x8*)&As16[node * LDP + c8] = v;
        }
    } else {    // fp32 input, optional norm+relu
        for (int t = tid; t < 64 * 32; t += 256) {
            int node = t >> 5, c4 = (t & 31) << 2;
            int n = n0 + node;
            float4 v = {0.f, 0.f, 0.f, 0.f};
            if (n < N_NODES) v = *(const float4*)((const float*)inp + (size_t)n * 128 + c4);
            if (donorm) {
                v.x = fmaxf(v.x * Sc[c4]     + Sh[c4],     0.f);
                v.y = fmaxf(v.y * Sc[c4 + 1] + Sh[c4 + 1], 0.f);
                v.z = fmaxf(v.z * Sc[c4 + 2] + Sh[c4 + 2], 0.f);
                v.w = fmaxf(v.w * Sc[c4 + 3] + Sh[c4 + 3], 0.f);
            }
            ushort4 h;
            h.x = f2b(v.x); h.y = f2b(v.y); h.z = f2b(v.z); h.w = f2b(v.w);
            *(ushort4*)&As16[node * LDP + c4] = h;
        }
    }
    // stage B^T [64 j][128 k]: vector global read along j, scalar LDS scatter
    if (fb) {
        for (int t = tid; t < 128 * 8; t += 256) {
            int k = t >> 3, j8 = (t & 7) << 3;
            bf16x8 v = *(const bf16x8*)((const u16*)W + k * 128 + jb + j8);
            #pragma unroll
            for (int q = 0; q < 8; ++q) Bs16[(j8 + q) * LDP + k] = (u16)v[q];
        }
    } else {
        for (int t = tid; t < 128 * 16; t += 256) {
            int k = t >> 4, j4 = (t & 15) << 2;
            float4 v = *(const float4*)((const float*)W + k * 128 + jb + j4);
            Bs16[(j4 + 0) * LDP + k] = f2b(v.x);
            Bs16[(j4 + 1) * LDP + k] = f2b(v.y);
            Bs16[(j4 + 2) * LDP + k] = f2b(v.z);
            Bs16[(j4 + 3) * LDP + k] = f2b(v.w);
        }
    }
    __syncthreads();

    int wv = tid >> 6, lane = tid & 63;
    int quad = lane >> 4, r = lane & 15;
    int m0 = wv * 16;
    f32x4 acc[4] = {{0.f,0.f,0.f,0.f},{0.f,0.f,0.f,0.f},
                    {0.f,0.f,0.f,0.f},{0.f,0.f,0.f,0.f}};
    #pragma unroll
    for (int ks = 0; ks < 4; ++ks) {
        int ko = ks * 32 + quad * 8;
        bf16x8 af = *(const bf16x8*)&As16[(m0 + r) * LDP + ko];
        #pragma unroll
        for (int t = 0; t < 4; ++t) {
            bf16x8 bfr = *(const bf16x8*)&Bs16[(t * 16 + r) * LDP + ko];
            acc[t] = __builtin_amdgcn_mfma_f32_16x16x32_bf16(af, bfr, acc[t], 0, 0, 0);
        }
    }
    #pragma unroll
    for (int t = 0; t < 4; ++t) {
        int j = jb + t * 16 + r;
        float bj = ldf(bi, j, fb);
        #pragma unroll
        for (int reg = 0; reg < 4; ++reg) {
            int node = n0 + m0 + quad * 4 + reg;
            if (node < N_NODES) dst[node * 128 + j] = f2b(acc[t][reg] + bj);
        }
    }
}

// ------ per-dst online-softmax aggregation: 1 wave/node, 2-edge ILP ------
// lane owns channel pair (2l,2l+1); lanes 0-31 = head0, 32-63 = head1.
__global__ __launch_bounds__(64) void agg_kernel(const u32* __restrict__ XLw,
        const u32* __restrict__ XRw, const void* __restrict__ att,
        const int* __restrict__ fmt,
        const int* __restrict__ indptr, const int* __restrict__ srcs,
        float2* __restrict__ OUT2) {
    int lane = threadIdx.x;
    int n = blockIdx.x;
    int fb = fmt[0];
    u32 wr = XRw[n * 64 + lane];
    float xr0 = wlo(wr), xr1 = whi(wr);
    float a0 = ldf(att, 2 * lane, fb);
    float a1 = ldf(att, 2 * lane + 1, fb);
    int beg = indptr[n], end = indptr[n + 1];
    // two independent online-softmax states (ILP)
    float mA = -1e30f, dA = 0.f, accA0 = 0.f, accA1 = 0.f;
    float mB = -1e30f, dB = 0.f, accB0 = 0.f, accB1 = 0.f;
    int i = beg;
    for (; i + 1 < end; i += 2) {
        int sA = srcs[i], sB = srcs[i + 1];
        u32 wA = XLw[sA * 64 + lane];
        u32 wB = XLw[sB * 64 + lane];
        float xA0 = wlo(wA), xA1 = whi(wA);
        float xB0 = wlo(wB), xB1 = whi(wB);
        float tA0 = xA0 + xr0; tA0 = (tA0 > 0.f) ? tA0 : NEG * tA0;
        float tA1 = xA1 + xr1; tA1 = (tA1 > 0.f) ? tA1 : NEG * tA1;
        float tB0 = xB0 + xr0; tB0 = (tB0 > 0.f) ? tB0 : NEG * tB0;
        float tB1 = xB1 + xr1; tB1 = (tB1 > 0.f) ? tB1 : NEG * tB1;
        float pA = tA0 * a0 + tA1 * a1;
        float pB = tB0 * a0 + tB1 * a1;
        pA += __shfl_xor(pA, 1);  pB += __shfl_xor(pB, 1);
        pA += __shfl_xor(pA, 2);  pB += __shfl_xor(pB, 2);
        pA += __shfl_xor(pA, 4);  pB += __shfl_xor(pB, 4);
        pA += __shfl_xor(pA, 8);  pB += __shfl_xor(pB, 8);
        pA += __shfl_xor(pA, 16); pB += __shfl_xor(pB, 16);
        float nmA = fmaxf(mA, pA); float scA = __expf(mA - nmA); float wA2 = __expf(pA - nmA);
        float nmB = fmaxf(mB, pB); float scB = __expf(mB - nmB); float wB2 = __expf(pB - nmB);
        accA0 = accA0 * scA + wA2 * xA0; accA1 = accA1 * scA + wA2 * xA1;
        dA = dA * scA + wA2; mA = nmA;
        accB0 = accB0 * scB + wB2 * xB0; accB1 = accB1 * scB + wB2 * xB1;
        dB = dB * scB + wB2; mB = nmB;
    }
    if (i < end) {   // peel last odd edge into state A
        int s = srcs[i];
        u32 wl = XLw[s * 64 + lane];
        float xl0 = wlo(wl), xl1 = whi(wl);
        float t0 = xl0 + xr0; t0 = (t0 > 0.f) ? t0 : NEG * t0;
        float t1 = xl1 + xr1; t1 = (t1 > 0.f) ? t1 : NEG * t1;
        float p = t0 * a0 + t1 * a1;
        p += __shfl_xor(p, 1);
        p += __shfl_xor(p, 2);
        p += __shfl_xor(p, 4);
        p += __shfl_xor(p, 8);
        p += __shfl_xor(p, 16);
        float nm = fmaxf(mA, p); float sc = __expf(mA - nm); float w = __expf(p - nm);
        accA0 = accA0 * sc + w * xl0; accA1 = accA1 * sc + w * xl1;
        dA = dA * sc + w; mA = nm;
    }
    // exact merge of the two softmax states
    float nm = fmaxf(mA, mB);
    float sA = __expf(mA - nm), sB = __expf(mB - nm);
    float acc0 = accA0 * sA + accB0 * sB;
    float acc1 = accA1 * sA + accB1 * sB;
    float d = dA * sA + dB * sB;
    float inv = 1.f / (d + 1e-16f);
    float2 o; o.x = acc0 * inv; o.y = acc1 * inv;
    OUT2[n * 64 + lane] = o;
}

// ---------------- GraphNorm stats ----------------
__global__ void zero_small(float* __restrict__ p) { p[threadIdx.x] = 0.f; }

__global__ __launch_bounds__(256) void colstats(const float* __restrict__ OUT,
        const void* __restrict__ bias, const int* __restrict__ fmt,
        float* __restrict__ S1, float* __restrict__ S2) {
    __shared__ float sh1[256], sh2[256];
    int tid = threadIdx.x;
    int c = tid & 127, half = tid >> 7;
    float bf = ldf(bias, c, fmt[0]);
    float s1 = 0.f, s2 = 0.f;
    for (int r = blockIdx.x * 2 + half; r < N_NODES; r += gridDim.x * 2) {
        float t = OUT[r * 128 + c] + bf;
        s1 += t; s2 += t * t;
    }
    sh1[tid] = s1; sh2[tid] = s2; __syncthreads();
    if (tid < 128) {
        atomicAdd(&S1[c], sh1[tid] + sh1[tid + 128]);
        atomicAdd(&S2[c], sh2[tid] + sh2[tid + 128]);
    }
}

__global__ void finalize_norm(const float* __restrict__ S1, const float* __restrict__ S2,
        const void* __restrict__ gamma, const void* __restrict__ beta,
        const void* __restrict__ msc, const void* __restrict__ bias,
        const int* __restrict__ fmt,
        float* __restrict__ scaleA, float* __restrict__ shiftB) {
    int c = threadIdx.x;
    if (c >= 128) return;
    int fb = fmt[0];
    const float invN = 1.f / (float)N_NODES;
    float mean = S1[c] * invN;
    float ex2  = S2[c] * invN;
    float ms = ldf(msc, c, fb);
    float var = ex2 - 2.f * ms * mean * mean + ms * ms * mean * mean;
    float rstd = rsqrtf(var + 1e-5f);
    float A = ldf(gamma, c, fb) * rstd;
    scaleA[c] = A;
    shiftB[c] = ldf(beta, c, fb) - A * (ms * mean - ldf(bias, c, fb));
}

// ---------------- fused MLP head with fused input norm+relu, fp32 out ---------
__global__ __launch_bounds__(256) void mlp_kernel(const float* __restrict__ H,
        const void* __restrict__ w1, const void* __restrict__ b1,
        const void* __restrict__ w2, const void* __restrict__ b2,
        const float* __restrict__ nscale, const float* __restrict__ nshift,
        const int* __restrict__ fmt,
        float* __restrict__ out) {
    __shared__ float W1s[128 * 64];
    __shared__ float W2s[128];
    __shared__ float b1s[64];
    __shared__ float Sc[128], Sh[128];
    int tid = threadIdx.x;
    int fb = fmt[0];
    if (fb) {
        for (int t = tid; t < 128 * 8; t += 256) {
            int row8 = t << 3;
            bf16x8 v = *(const bf16x8*)((const u16*)w1 + row8);
            #pragma unroll
            for (int q = 0; q < 8; ++q) W1s[row8 + q] = b2f((u16)v[q]);
        }
    } else {
        for (int t = tid; t < 128 * 64; t += 256) W1s[t] = ((const float*)w1)[t];
    }
    if (tid < 128) { W2s[tid] = ldf(w2, tid, fb); Sc[tid] = nscale[tid]; Sh[tid] = nshift[tid]; }
    if (tid < 64)  b1s[tid] = ldf(b1, tid, fb);
    __syncthreads();
    int n = blockIdx.x * 256 + tid;
    if (n >= N_NODES) return;
    float z[64];
    #pragma unroll
    for (int j = 0; j < 64; j++) z[j] = b1s[j];
    for (int kb = 0; kb < 128; kb += 16) {
        float h[16];
        #pragma unroll
        for (int t = 0; t < 4; t++) {
            float4 v = *(const float4*)&H[n * 128 + kb + t * 4];
            int c = kb + t * 4;
            h[4 * t]     = fmaxf(v.x * Sc[c]     + Sh[c],     0.f);
            h[4 * t + 1] = fmaxf(v.y * Sc[c + 1] + Sh[c + 1], 0.f);
            h[4 * t + 2] = fmaxf(v.z * Sc[c + 2] + Sh[c + 2], 0.f);
            h[4 * t + 3] = fmaxf(v.w * Sc[c + 3] + Sh[c + 3], 0.f);
        }
        #pragma unroll
        for (int i = 0; i < 16; i++) {
            float hv = h[i];
            const float* wrow = &W1s[(kb + i) * 64];
            #pragma unroll
            for (int j = 0; j < 64; j += 4) {
                const float4 w = *(const float4*)&wrow[j];
                z[j]     += hv * w.x;
                z[j + 1] += hv * w.y;
                z[j + 2] += hv * w.z;
                z[j + 3] += hv * w.w;
            }
        }
    }
    float o0 = ldf(b2, 0, fb), o1 = ldf(b2, 1, fb);
    #pragma unroll
    for (int j = 0; j < 64; j++) {
        float zr = fmaxf(z[j], 0.f);
        o0 += zr * W2s[j * 2];
        o1 += zr * W2s[j * 2 + 1];
    }
    if (o0 != o0) o0 = 12345.f;
    if (o1 != o1) o1 = 12345.f;
    float2 o; o.x = o0; o.y = o1;
    ((float2*)out)[n] = o;
}

// ---------------- launch ----------------
extern "C" void kernel_launch(void* const* d_in, const int* in_sizes, int n_in,
                              void* d_out, int out_size, void* d_ws, size_t ws_size,
                              hipStream_t stream) {
    (void)in_sizes; (void)n_in; (void)out_size; (void)ws_size;
    const void* x    = d_in[0];
    const int*  ei   = (const int*)d_in[1];
    const void* Wl0  = d_in[2];
    const void* bl0  = d_in[3];
    const void* Wr0  = d_in[4];
    const void* br0  = d_in[5];
    const void* att0 = d_in[6];
    const void* bias0= d_in[7];
    const void* Wl1  = d_in[8];
    const void* bl1  = d_in[9];
    const void* Wr1  = d_in[10];
    const void* br1  = d_in[11];
    const void* att1 = d_in[12];
    const void* bias1= d_in[13];
    const void* g0   = d_in[14];
    const void* be0  = d_in[15];
    const void* ms0  = d_in[16];
    const void* g1   = d_in[17];
    const void* be1  = d_in[18];
    const void* ms1  = d_in[19];
    const void* W1   = d_in[20];
    const void* b1   = d_in[21];
    const void* W2   = d_in[22];
    const void* b2   = d_in[23];

    char* ws = (char*)d_ws;
    const size_t NF2 = (size_t)N_NODES * 128 * 2;
    const size_t NF4 = (size_t)N_NODES * 128 * 4;
    u16*   XLb = (u16*)(ws);
    u16*   XRb = (u16*)(ws + NF2);
    float* B2  = (float*)(ws + 2 * NF2);
    char* small = ws + 2 * NF2 + NF4;               // 51.2 MB offset
    float* S1     = (float*)(small);
    float* S2     = (float*)(small + 512);
    float* scaleA = (float*)(small + 1024);
    float* shiftB = (float*)(small + 1536);
    int*   flag   = (int*)(small + 2048);
    int*   bsum   = (int*)(small + 2112);
    int*   boff   = (int*)(small + 2368);
    int*   indptr = (int*)(small + 4096);
    int*   cursor = indptr + (N_NODES + 64);
    int*   cnt    = cursor + (N_NODES + 64);
    int*   srcs   = cnt + (N_NODES + 64);
    // footprint ~55.2 MB (proven budget)

    const int* fX   = &flag[0];
    const int* fFP  = &flag[1];
    const int* fPar = &flag[3];
    const int NB_SCAN = (N_NODES + SCAN_CHUNK - 1) / SCAN_CHUNK;

    fill_out<<<(N_NODES + 255) / 256, 256, 0, stream>>>((float*)d_out);
    probe_fmt<<<1, 64, 0, stream>>>((const u32*)x, 50000, &flag[0]);
    probe_fmt<<<1, 64, 0, stream>>>((const u32*)Wl0, 128, &flag[3]);
    zero_flag1<<<1, 64, 0, stream>>>(flag);
    detect_i64<<<1, 64, 0, stream>>>(ei, flag);

    init_cnt<<<(N_NODES + 255) / 256, 256, 0, stream>>>(cnt);
    hist_kernel<<<(NE + 255) / 256, 256, 0, stream>>>(ei, flag, cnt);
    scan_a<<<NB_SCAN, 256, 0, stream>>>(cnt, bsum);
    scan_b<<<1, 64, 0, stream>>>(bsum, boff, NB_SCAN);
    scan_c<<<NB_SCAN, 256, 0, stream>>>(cnt, boff, indptr, cursor);
    scatter_kernel<<<(NETOT + 255) / 256, 256, 0, stream>>>(ei, flag, cursor, srcs);

    dim3 ggemm((N_NODES + 63) / 64, 4);

    for (int layer = 0; layer < 2; ++layer) {
        const void* Wl = layer ? Wl1 : Wl0;  const void* bl = layer ? bl1 : bl0;
        const void* Wr = layer ? Wr1 : Wr0;  const void* br = layer ? br1 : br0;
        const void* at = layer ? att1 : att0;
        const void* bi = layer ? bias1 : bias0;
        const void* gm = layer ? g1 : g0;    const void* bt = layer ? be1 : be0;
        const void* mS = layer ? ms1 : ms0;
        const void* inp = layer ? (const void*)B2 : x;
        const int* fin  = layer ? fFP : fX;
        const float* ns = layer ? scaleA : nullptr;   // layer1 input: fused norm+relu
        const float* nh = layer ? shiftB : nullptr;

        zero_small<<<1, 256, 0, stream>>>(S1);
        gemm_xf<<<ggemm, 256, 0, stream>>>(inp, fin, fPar, Wl, bl, Wr, br, ns, nh,
                                           XLb, XRb);
        agg_kernel<<<N_NODES, 64, 0, stream>>>((const u32*)XLb, (const u32*)XRb,
                                               at, fPar, indptr, srcs, (float2*)B2);
        colstats<<<256, 256, 0, stream>>>(B2, bi, fPar, S1, S2);
        finalize_norm<<<1, 128, 0, stream>>>(S1, S2, gm, bt, mS, bi, fPar, scaleA, shiftB);
    }

    mlp_kernel<<<(N_NODES + 255) / 256, 256, 0, stream>>>(B2, W1, b1, W2, b2,
                                                          scaleA, shiftB, fPar,
                                                          (float*)d_out);
}